// Round 1
// baseline (1048.751 us; speedup 1.0000x reference)
//
#include <hip/hip_runtime.h>

#define B_SZ 2
#define KNB 16

// ---------------------------------------------------------------- KNN ----
__launch_bounds__(256)
__global__ void knn_partial_kernel(const float* __restrict__ q, const float* __restrict__ t,
                                   float* __restrict__ pd, int* __restrict__ pi, int N)
{
  const int SEGLEN = 512;              // N/8
  int b = blockIdx.z, seg = blockIdx.y;
  int qi = blockIdx.x * blockDim.x + threadIdx.x;
  __shared__ __align__(16) float4 ts[512];
  const float* tb = t + (size_t)b * 3 * N;
  for (int i = threadIdx.x; i < SEGLEN; i += blockDim.x) {
    int m = seg * SEGLEN + i;
    float x = tb[m], y = tb[N + m], zc = tb[2 * N + m];
    ts[i] = make_float4(x, y, zc, x * x + y * y + zc * zc);
  }
  __syncthreads();
  const float* qb = q + (size_t)b * 3 * N;
  float qx = qb[qi], qy = qb[N + qi], qz = qb[2 * N + qi];
  float qq = qx * qx + qy * qy + qz * qz;
  float bd[16]; int bi[16];
#pragma unroll
  for (int j = 0; j < 16; ++j) { bd[j] = 3.0e38f; bi[j] = 0; }
#pragma unroll 4
  for (int i = 0; i < SEGLEN; ++i) {
    float4 tv = ts[i];
    float d = (qq + tv.w) - 2.0f * (qx * tv.x + qy * tv.y + qz * tv.z);
    if (d < bd[15]) {
      bd[15] = d; bi[15] = seg * SEGLEN + i;
#pragma unroll
      for (int j = 15; j > 0; --j) {
        if (bd[j] < bd[j - 1]) {
          float td = bd[j]; bd[j] = bd[j - 1]; bd[j - 1] = td;
          int ti = bi[j]; bi[j] = bi[j - 1]; bi[j - 1] = ti;
        }
      }
    }
  }
  size_t base = (((size_t)b * N + qi) * 8 + seg) * 16;
#pragma unroll
  for (int j = 0; j < 16; ++j) { pd[base + j] = bd[j]; pi[base + j] = bi[j]; }
}

__launch_bounds__(256)
__global__ void knn_merge_kernel(const float* __restrict__ pd, const int* __restrict__ pi,
                                 int* __restrict__ idx, long total)
{
  long qid = (long)blockIdx.x * blockDim.x + threadIdx.x;
  if (qid >= total) return;
  const float* p = pd + qid * 128;
  const int* ii = pi + qid * 128;
  float bd[16]; int bi[16];
#pragma unroll
  for (int j = 0; j < 16; ++j) { bd[j] = 3.0e38f; bi[j] = 0; }
#pragma unroll 4
  for (int s = 0; s < 128; ++s) {
    float d = p[s];
    if (d < bd[15]) {
      int id = ii[s];
      bd[15] = d; bi[15] = id;
#pragma unroll
      for (int j = 15; j > 0; --j) {
        if (bd[j] < bd[j - 1]) {
          float td = bd[j]; bd[j] = bd[j - 1]; bd[j - 1] = td;
          int ti = bi[j]; bi[j] = bi[j - 1]; bi[j - 1] = ti;
        }
      }
    }
  }
#pragma unroll
  for (int j = 0; j < 16; ++j) idx[qid * 16 + j] = bi[j];
}

// --------------------------------------------------------- projections ----
// out[b][n][o] = bias[o] + sum_segs scale * W[o, coff+c] * seg[b, c(n)]
__device__ __forceinline__ void seg_accum(const float* __restrict__ p, int cnt,
    const float* __restrict__ WL, int coff, int sC, int sN, float fs,
    long n0, float acc[4])
{
#pragma unroll 4
  for (int c = 0; c < cnt; ++c) {
    float w = WL[coff + c] * fs;
#pragma unroll
    for (int m = 0; m < 4; ++m)
      acc[m] = fmaf(w, p[(size_t)c * sC + (size_t)(n0 + m) * sN], acc[m]);
  }
}

__launch_bounds__(256)
__global__ void proj_kernel(
    const float* __restrict__ W, int wld, const float* __restrict__ bias,
    float* __restrict__ out, int OUT, int N,
    const float* __restrict__ s0, int c0, int o0, int sC0, int sN0, float f0,
    const float* __restrict__ s1, int c1, int o1, int sC1, int sN1, float f1,
    const float* __restrict__ s2, int c2, int o2, int sC2, int sN2, float f2,
    const float* __restrict__ s3, int c3, int o3, int sC3, int sN3, float f3)
{
  int b = blockIdx.y;
  int lane = threadIdx.x % OUT;
  int grp = threadIdx.x / OUT;
  int grps = blockDim.x / OUT;
  long n0 = ((long)blockIdx.x * grps + grp) * 4;
  if (n0 >= N) return;
  float acc[4];
  float bv = bias ? bias[lane] : 0.0f;
#pragma unroll
  for (int m = 0; m < 4; ++m) acc[m] = bv;
  const float* WL = W + (size_t)lane * wld;
  if (c0 > 0) seg_accum(s0 + (size_t)b * c0 * N, c0, WL, o0, sC0, sN0, f0, n0, acc);
  if (c1 > 0) seg_accum(s1 + (size_t)b * c1 * N, c1, WL, o1, sC1, sN1, f1, n0, acc);
  if (c2 > 0) seg_accum(s2 + (size_t)b * c2 * N, c2, WL, o2, sC2, sN2, f2, n0, acc);
  if (c3 > 0) seg_accum(s3 + (size_t)b * c3 * N, c3, WL, o3, sC3, sN3, f3, n0, acc);
#pragma unroll
  for (int m = 0; m < 4; ++m)
    out[((size_t)b * N + n0 + m) * OUT + lane] = acc[m];
}

// ------------------------------------------------------------- groupnorm ----
__launch_bounds__(256)
__global__ void gn1_stats_kernel(const float* __restrict__ G1, const float* __restrict__ Bx,
    const int* __restrict__ idx0, float* __restrict__ stats1, int N)
{
  __shared__ float red[4][4][2];
  int b = blockIdx.y;
  int lane = threadIdx.x & 63, wav = threadIdx.x >> 6;
  float sum = 0.f, sq = 0.f;
  for (int n = blockIdx.x * 4 + wav; n < N; n += gridDim.x * 4) {
    const int* ip = idx0 + ((size_t)b * N + n) * 16;
    float bx = Bx[((size_t)b * N + n) * 64 + lane];
#pragma unroll
    for (int k = 0; k < 16; ++k) {
      int m = ip[k];
      float y = G1[((size_t)b * N + m) * 64 + lane] - bx;
      sum += y; sq += y * y;
    }
  }
#pragma unroll
  for (int off = 1; off < 16; off <<= 1) {
    sum += __shfl_xor(sum, off, 64);
    sq += __shfl_xor(sq, off, 64);
  }
  int g = lane >> 4;
  if ((lane & 15) == 0) { red[wav][g][0] = sum; red[wav][g][1] = sq; }
  __syncthreads();
  if (threadIdx.x < 8) {
    int gg = threadIdx.x >> 1, s = threadIdx.x & 1;
    float v = red[0][gg][s] + red[1][gg][s] + red[2][gg][s] + red[3][gg][s];
    atomicAdd(&stats1[(b * 4 + gg) * 2 + s], v);
  }
}

__global__ void gn_finalize_kernel(const float* __restrict__ raw, float* __restrict__ mi, float cnt)
{
  int i = threadIdx.x;
  if (i < 8) {
    float s = raw[i * 2], q = raw[i * 2 + 1];
    float m = s / cnt;
    float v = q / cnt - m * m;
    mi[i * 2] = m;
    mi[i * 2 + 1] = rsqrtf(v + 1e-5f);
  }
}

// ------------------------------------------------------------- flow conv2 ----
__launch_bounds__(256)
__global__ void conv2_kernel(const float* __restrict__ G1, const float* __restrict__ Bx,
    const int* __restrict__ idx0, const float* __restrict__ fw2, const float* __restrict__ fb2,
    const float* __restrict__ fg1, const float* __restrict__ fbe1,
    const float* __restrict__ mi1, float* __restrict__ y2max, float* __restrict__ y2min,
    float* __restrict__ stats2, int N)
{
  __shared__ __align__(16) float Wl[64][68];
  __shared__ __align__(16) float x2[4][16][64];
  __shared__ float red[4][4][2];
  int b = blockIdx.y;
  int lane = threadIdx.x & 63, wav = threadIdx.x >> 6;
  for (int i = threadIdx.x; i < 64 * 64; i += 256) Wl[i >> 6][i & 63] = fw2[i];
  int g = lane >> 4;
  float mu1 = mi1[(b * 4 + g) * 2], inv1 = mi1[(b * 4 + g) * 2 + 1];
  float sc1 = fg1[lane] * inv1;
  float sh1 = fbe1[lane] - mu1 * sc1;
  float fb2l = fb2[lane];
  float sum = 0.f, sq = 0.f;
  __syncthreads();
  for (int n = blockIdx.x * 4 + wav; n < N; n += gridDim.x * 4) {
    const int* ip = idx0 + ((size_t)b * N + n) * 16;
    float bx = Bx[((size_t)b * N + n) * 64 + lane];
#pragma unroll
    for (int k = 0; k < 16; ++k) {
      int m = ip[k];
      float y = G1[((size_t)b * N + m) * 64 + lane] - bx;
      float tv = y * sc1 + sh1;
      x2[wav][k][lane] = tv >= 0.f ? tv : 0.1f * tv;
    }
    __syncthreads();
    float acc[16];
#pragma unroll
    for (int k = 0; k < 16; ++k) acc[k] = fb2l;
    for (int c4 = 0; c4 < 16; ++c4) {
      float4 w4 = *(const float4*)&Wl[lane][c4 * 4];
#pragma unroll
      for (int k = 0; k < 16; ++k) {
        float4 x4 = *(const float4*)&x2[wav][k][c4 * 4];
        acc[k] = fmaf(w4.x, x4.x, acc[k]);
        acc[k] = fmaf(w4.y, x4.y, acc[k]);
        acc[k] = fmaf(w4.z, x4.z, acc[k]);
        acc[k] = fmaf(w4.w, x4.w, acc[k]);
      }
    }
    float mx = -3.0e38f, mn = 3.0e38f;
#pragma unroll
    for (int k = 0; k < 16; ++k) {
      mx = fmaxf(mx, acc[k]); mn = fminf(mn, acc[k]);
      sum += acc[k]; sq += acc[k] * acc[k];
    }
    y2max[((size_t)b * N + n) * 64 + lane] = mx;
    y2min[((size_t)b * N + n) * 64 + lane] = mn;
    __syncthreads();
  }
#pragma unroll
  for (int off = 1; off < 16; off <<= 1) {
    sum += __shfl_xor(sum, off, 64);
    sq += __shfl_xor(sq, off, 64);
  }
  if ((lane & 15) == 0) { red[wav][g][0] = sum; red[wav][g][1] = sq; }
  __syncthreads();
  if (threadIdx.x < 8) {
    int gg = threadIdx.x >> 1, s = threadIdx.x & 1;
    float v = red[0][gg][s] + red[1][gg][s] + red[2][gg][s] + red[3][gg][s];
    atomicAdd(&stats2[(b * 4 + gg) * 2 + s], v);
  }
}

__launch_bounds__(256)
__global__ void flow_feat_kernel(const float* __restrict__ y2max, const float* __restrict__ y2min,
    const float* __restrict__ mi2, const float* __restrict__ fg2, const float* __restrict__ fbe2,
    float* __restrict__ ff, int N)
{
  size_t i = (size_t)blockIdx.x * blockDim.x + threadIdx.x;
  if (i >= (size_t)B_SZ * N * 64) return;
  int c = i & 63;
  size_t pn = i >> 6;
  int b = (int)(pn / N);
  int g = c >> 4;
  float mu = mi2[(b * 4 + g) * 2], inv = mi2[(b * 4 + g) * 2 + 1];
  float sc = fg2[c] * inv;
  float sh = fbe2[c] - mu * sc;
  float y = (sc >= 0.0f) ? y2max[i] : y2min[i];
  float v = y * sc + sh;
  ff[i] = v >= 0.0f ? v : 0.1f * v;
}

// ------------------------------------------------------------------ gates ----
__launch_bounds__(256)
__global__ void gate_zr_kernel(const float* __restrict__ Sz, const float* __restrict__ Xz,
    const float* __restrict__ Sr, const float* __restrict__ Xr,
    const float* __restrict__ state, const int* __restrict__ idx0,
    float* __restrict__ zo, float* __restrict__ rs, int N)
{
  int b = blockIdx.y;
  int lane = threadIdx.x & 63, wav = threadIdx.x >> 6;
  int n = blockIdx.x * 4 + wav;
  const int* ip = idx0 + ((size_t)b * N + n) * 16;
  float mz = -3.0e38f, mr = -3.0e38f;
#pragma unroll
  for (int k = 0; k < 16; ++k) {
    size_t mo = ((size_t)b * N + ip[k]) * 64 + lane;
    mz = fmaxf(mz, Sz[mo]);
    mr = fmaxf(mr, Sr[mo]);
  }
  size_t no = ((size_t)b * N + n) * 64 + lane;
  float z = 1.f / (1.f + expf(-(mz - Xz[no])));
  float r = 1.f / (1.f + expf(-(mr - Xr[no])));
  zo[no] = z;
  rs[no] = r * state[((size_t)b * 64 + lane) * N + n];
}

__launch_bounds__(256)
__global__ void gate_q_ns_kernel(const float* __restrict__ Sq, const float* __restrict__ Xq,
    const float* __restrict__ zo, const float* __restrict__ state, const int* __restrict__ idx0,
    float* __restrict__ ns, int N)
{
  int b = blockIdx.y;
  int lane = threadIdx.x & 63, wav = threadIdx.x >> 6;
  int n = blockIdx.x * 4 + wav;
  const int* ip = idx0 + ((size_t)b * N + n) * 16;
  float mq = -3.0e38f;
#pragma unroll
  for (int k = 0; k < 16; ++k)
    mq = fmaxf(mq, Sq[((size_t)b * N + ip[k]) * 64 + lane]);
  size_t no = ((size_t)b * N + n) * 64 + lane;
  float q = tanhf(mq - Xq[no]);
  float z = zo[no];
  float st = state[((size_t)b * 64 + lane) * N + n];
  ns[no] = (1.f - z) * st + z * q;
}

// ------------------------------------------------------------------ align ----
__launch_bounds__(256)
__global__ void align_kernel(const float* __restrict__ U, const float* __restrict__ V,
    const float* __restrict__ wa2, const float* __restrict__ ba2,
    const float* __restrict__ ns, const int* __restrict__ idx1,
    float* __restrict__ out, int N)
{
  __shared__ __align__(16) float Wl[64][132];
  __shared__ __align__(16) float xk[4][16][128];
  int b = blockIdx.y;
  int lane = threadIdx.x & 63, wav = threadIdx.x >> 6;
  for (int i = threadIdx.x; i < 64 * 128; i += 256) Wl[i >> 7][i & 127] = wa2[i];
  float ba = ba2[lane];
  __syncthreads();
  int n = blockIdx.x * 4 + wav;
  const int* ip = idx1 + ((size_t)b * N + n) * 16;
  int mk[16];
#pragma unroll
  for (int k = 0; k < 16; ++k) mk[k] = ip[k];
  const float* Vp = V + ((size_t)b * N + n) * 128;
  float v0 = Vp[lane], v1 = Vp[64 + lane];
#pragma unroll
  for (int k = 0; k < 16; ++k) {
    const float* Up = U + ((size_t)b * N + mk[k]) * 128;
    float a = Up[lane] + v0;
    float c2 = Up[64 + lane] + v1;
    xk[wav][k][lane] = a >= 0.f ? a : 0.1f * a;
    xk[wav][k][64 + lane] = c2 >= 0.f ? c2 : 0.1f * c2;
  }
  __syncthreads();
  float acc[16];
#pragma unroll
  for (int k = 0; k < 16; ++k) acc[k] = ba;
  for (int c4 = 0; c4 < 32; ++c4) {
    float4 w4 = *(const float4*)&Wl[lane][c4 * 4];
#pragma unroll
    for (int k = 0; k < 16; ++k) {
      float4 x4 = *(const float4*)&xk[wav][k][c4 * 4];
      acc[k] = fmaf(w4.x, x4.x, acc[k]);
      acc[k] = fmaf(w4.y, x4.y, acc[k]);
      acc[k] = fmaf(w4.z, x4.z, acc[k]);
      acc[k] = fmaf(w4.w, x4.w, acc[k]);
    }
  }
  float m = acc[0];
#pragma unroll
  for (int k = 1; k < 16; ++k) m = fmaxf(m, acc[k]);
  float s = 0.f;
#pragma unroll
  for (int k = 0; k < 16; ++k) { acc[k] = expf(acc[k] - m); s += acc[k]; }
  float rinv = 1.0f / s;
  float o = 0.f;
#pragma unroll
  for (int k = 0; k < 16; ++k)
    o += acc[k] * rinv * ns[((size_t)b * N + mk[k]) * 64 + lane];
  out[((size_t)b * 64 + lane) * N + n] = o;
}

// ------------------------------------------------------------------ launch ----
extern "C" void kernel_launch(void* const* d_in, const int* in_sizes, int n_in,
                              void* d_out, int out_size, void* d_ws, size_t ws_size,
                              hipStream_t stream) {
  (void)n_in; (void)out_size; (void)ws_size;
  const float* xyz0 = (const float*)d_in[0];
  const float* xyz1 = (const float*)d_in[1];
  const float* state = (const float*)d_in[2];
  const float* corr0 = (const float*)d_in[3];
  const float* feat0 = (const float*)d_in[4];
  const float* feat1 = (const float*)d_in[5];
  const float* flow0 = (const float*)d_in[6];
  const float* fw1 = (const float*)d_in[7];
  const float* fb1 = (const float*)d_in[8];
  const float* fg1 = (const float*)d_in[9];
  const float* fbe1 = (const float*)d_in[10];
  const float* fw2 = (const float*)d_in[11];
  const float* fb2 = (const float*)d_in[12];
  const float* fg2 = (const float*)d_in[13];
  const float* fbe2 = (const float*)d_in[14];
  const float* wz = (const float*)d_in[15];
  const float* bz = (const float*)d_in[16];
  const float* wr = (const float*)d_in[17];
  const float* br = (const float*)d_in[18];
  const float* wq = (const float*)d_in[19];
  const float* bq = (const float*)d_in[20];
  const float* wa1 = (const float*)d_in[21];
  const float* ba1 = (const float*)d_in[22];
  const float* wa2 = (const float*)d_in[23];
  const float* ba2 = (const float*)d_in[24];
  float* out = (float*)d_out;

  const int N = in_sizes[0] / (3 * B_SZ);  // 4096
  char* wsb = (char*)d_ws;
  size_t off = 0;
  auto take = [&](size_t bytes) -> char* {
    char* p = wsb + off;
    off += (bytes + 255) & ~(size_t)255;
    return p;
  };
  const size_t PN = (size_t)B_SZ * N;
  float* pd   = (float*)take(PN * 8 * 16 * 4);
  int*   pi   = (int*)  take(PN * 8 * 16 * 4);
  int*   idx0 = (int*)  take(PN * 16 * 4);
  int*   idx1 = (int*)  take(PN * 16 * 4);
  float* G1   = (float*)take(PN * 64 * 4);
  float* Bx   = (float*)take(PN * 64 * 4);
  float* y2mx = (float*)take(PN * 64 * 4);
  float* y2mn = (float*)take(PN * 64 * 4);
  float* ff   = (float*)take(PN * 64 * 4);
  float* Sz   = (float*)take(PN * 64 * 4);
  float* Xz   = (float*)take(PN * 64 * 4);
  float* Sr   = (float*)take(PN * 64 * 4);
  float* Xr   = (float*)take(PN * 64 * 4);
  float* Sq   = (float*)take(PN * 64 * 4);
  float* Xq   = (float*)take(PN * 64 * 4);
  float* zg   = (float*)take(PN * 64 * 4);
  float* rs   = (float*)take(PN * 64 * 4);
  float* ns   = (float*)take(PN * 64 * 4);
  float* stats = (float*)take(256);
  float* raw1 = stats, *raw2 = stats + 16, *mi1 = stats + 32, *mi2 = stats + 48;
  float* U = pd;           // reuse KNN partial buffers (knn done before U/V written)
  float* V = (float*)pi;

  const float* FNUL = nullptr;
  const float cntv = 16.0f * N * 16.0f;

  hipMemsetAsync(raw1, 0, 32 * sizeof(float), stream);

  // KNN
  knn_partial_kernel<<<dim3(N / 256, 8, B_SZ), 256, 0, stream>>>(xyz0, xyz0, pd, pi, N);
  knn_merge_kernel<<<dim3((unsigned)(PN / 256)), 256, 0, stream>>>(pd, pi, idx0, (long)PN);
  knn_partial_kernel<<<dim3(N / 256, 8, B_SZ), 256, 0, stream>>>(xyz1, xyz0, pd, pi, N);
  knn_merge_kernel<<<dim3((unsigned)(PN / 256)), 256, 0, stream>>>(pd, pi, idx1, (long)PN);

  dim3 pj64(N / 16, B_SZ), pj128(N / 8, B_SZ);
  // flow conv1 factored: G1 = fw1[:,:3]@flow0 + fw1[:,3:]@xyz0 + fb1 ; Bx = fw1[:,3:]@xyz0
  proj_kernel<<<pj64, 256, 0, stream>>>(fw1, 6, fb1, G1, 64, N,
      flow0, 3, 0, N, 1, 1.f,  xyz0, 3, 3, N, 1, 1.f,
      FNUL, 0, 0, 1, 1, 0.f,   FNUL, 0, 0, 1, 1, 0.f);
  proj_kernel<<<pj64, 256, 0, stream>>>(fw1, 6, FNUL, Bx, 64, N,
      xyz0, 3, 3, N, 1, 1.f,   FNUL, 0, 0, 1, 1, 0.f,
      FNUL, 0, 0, 1, 1, 0.f,   FNUL, 0, 0, 1, 1, 0.f);

  gn1_stats_kernel<<<dim3(128, B_SZ), 256, 0, stream>>>(G1, Bx, idx0, raw1, N);
  gn_finalize_kernel<<<1, 64, 0, stream>>>(raw1, mi1, cntv);
  conv2_kernel<<<dim3(128, B_SZ), 256, 0, stream>>>(G1, Bx, idx0, fw2, fb2, fg1, fbe1,
      mi1, y2mx, y2mn, raw2, N);
  gn_finalize_kernel<<<1, 64, 0, stream>>>(raw2, mi2, cntv);
  flow_feat_kernel<<<dim3((unsigned)(PN * 64 / 256)), 256, 0, stream>>>(y2mx, y2mn, mi2, fg2, fbe2, ff, N);

  // gate projections: S* over targets, X* = Wxyz@xyz0 at query
  proj_kernel<<<pj64, 256, 0, stream>>>(wz, 195, bz, Sz, 64, N,
      corr0, 64, 0, N, 1, 1.f,  ff, 64, 64, 1, 64, 1.f,
      state, 64, 128, N, 1, 1.f, xyz0, 3, 192, N, 1, 1.f);
  proj_kernel<<<pj64, 256, 0, stream>>>(wz, 195, FNUL, Xz, 64, N,
      xyz0, 3, 192, N, 1, 1.f,  FNUL, 0, 0, 1, 1, 0.f,
      FNUL, 0, 0, 1, 1, 0.f,    FNUL, 0, 0, 1, 1, 0.f);
  proj_kernel<<<pj64, 256, 0, stream>>>(wr, 195, br, Sr, 64, N,
      corr0, 64, 0, N, 1, 1.f,  ff, 64, 64, 1, 64, 1.f,
      state, 64, 128, N, 1, 1.f, xyz0, 3, 192, N, 1, 1.f);
  proj_kernel<<<pj64, 256, 0, stream>>>(wr, 195, FNUL, Xr, 64, N,
      xyz0, 3, 192, N, 1, 1.f,  FNUL, 0, 0, 1, 1, 0.f,
      FNUL, 0, 0, 1, 1, 0.f,    FNUL, 0, 0, 1, 1, 0.f);

  gate_zr_kernel<<<dim3(N / 4, B_SZ), 256, 0, stream>>>(Sz, Xz, Sr, Xr, state, idx0, zg, rs, N);

  proj_kernel<<<pj64, 256, 0, stream>>>(wq, 195, bq, Sq, 64, N,
      corr0, 64, 0, N, 1, 1.f,  ff, 64, 64, 1, 64, 1.f,
      rs, 64, 128, 1, 64, 1.f,  xyz0, 3, 192, N, 1, 1.f);
  proj_kernel<<<pj64, 256, 0, stream>>>(wq, 195, FNUL, Xq, 64, N,
      xyz0, 3, 192, N, 1, 1.f,  FNUL, 0, 0, 1, 1, 0.f,
      FNUL, 0, 0, 1, 1, 0.f,    FNUL, 0, 0, 1, 1, 0.f);

  gate_q_ns_kernel<<<dim3(N / 4, B_SZ), 256, 0, stream>>>(Sq, Xq, zg, state, idx0, ns, N);

  // align projections: U over targets (feat0 + xyz0), V per query (feat1 - xyz1 + ba1)
  proj_kernel<<<pj128, 256, 0, stream>>>(wa1, 259, FNUL, U, 128, N,
      feat0, 128, 0, N, 1, 1.f, xyz0, 3, 256, N, 1, 1.f,
      FNUL, 0, 0, 1, 1, 0.f,    FNUL, 0, 0, 1, 1, 0.f);
  proj_kernel<<<pj128, 256, 0, stream>>>(wa1, 259, ba1, V, 128, N,
      feat1, 128, 128, N, 1, 1.f, xyz1, 3, 256, N, 1, -1.f,
      FNUL, 0, 0, 1, 1, 0.f,      FNUL, 0, 0, 1, 1, 0.f);

  align_kernel<<<dim3(N / 4, B_SZ), 256, 0, stream>>>(U, V, wa2, ba2, ns, idx1, out, N);
}

// Round 2
// 506.795 us; speedup vs baseline: 2.0694x; 2.0694x over previous
//
#include <hip/hip_runtime.h>

#define B_SZ 2
#define KNB 16

// ---------------------------------------------------------------- KNN ----
// Pack targets: [B,3,N] -> [B,N] float4(x,y,z, x^2+y^2+z^2)
__launch_bounds__(256)
__global__ void pack_kernel(const float* __restrict__ xyz, float4* __restrict__ out, int N)
{
  int b = blockIdx.y;
  int i = blockIdx.x * 256 + threadIdx.x;
  if (i >= N) return;
  const float* p = xyz + (size_t)b * 3 * N;
  float x = p[i], y = p[N + i], z = p[2 * N + i];
  out[(size_t)b * N + i] = make_float4(x, y, z, x * x + y * y + z * z);
}

// One wave per query. Top-16 kept lane-distributed (lanes 0..15, ascending).
__launch_bounds__(256)
__global__ void knn_wave_kernel(const float4* __restrict__ pk, const float* __restrict__ q,
                                int* __restrict__ idx, int N)
{
  __shared__ float sx[1024], sy[1024], sz[1024], sw[1024];
  int b = blockIdx.y;
  int lane = threadIdx.x & 63, wav = threadIdx.x >> 6;
  int qi = blockIdx.x * 4 + wav;
  const float* qb = q + (size_t)b * 3 * N;
  float qx = qb[qi], qy = qb[N + qi], qz = qb[2 * N + qi];
  float qq = qx * qx + qy * qy + qz * qz;
  float bd = 3.0e38f;   // this lane's element of the distributed sorted top-16
  int   bi = 0;
  float thr = 3.0e38f;  // current 16th-smallest (INF until list full)
  const float4* pb = pk + (size_t)b * N;
  for (int ch = 0; ch < N; ch += 1024) {
    __syncthreads();
    for (int i = threadIdx.x; i < 1024; i += 256) {
      float4 v = pb[ch + i];
      sx[i] = v.x; sy[i] = v.y; sz[i] = v.z; sw[i] = v.w;
    }
    __syncthreads();
    for (int sub = 0; sub < 1024; sub += 64) {
      int c = sub + lane;
      float dl = (qq + sw[c]) - 2.0f * (qx * sx[c] + qy * sy[c] + qz * sz[c]);
      unsigned long long qm = __ballot(dl < thr);
      while (qm) {  // wave-uniform loop over qualifying candidates, index order
        int l = __ffsll(qm) - 1;
        qm &= qm - 1;
        float dc = __shfl(dl, l);
        unsigned long long rm = __ballot(lane < 16 && bd <= dc);
        int pos = __popcll(rm);     // stable rank: ties keep earlier index first
        if (pos < 16) {
          int ic = ch + sub + l;
          float pbd = __shfl(bd, lane - 1);
          int   pbi = __shfl(bi, lane - 1);
          if (lane < 16) {
            if (lane == pos)      { bd = dc;  bi = ic; }
            else if (lane > pos)  { bd = pbd; bi = pbi; }
          }
          thr = __shfl(bd, 15);
        }
      }
    }
  }
  if (lane < 16) idx[((size_t)b * N + qi) * 16 + lane] = bi;
}

// --------------------------------------------------------- projections ----
// out[b][n][o] = bias[o] + sum_segs scale * W[o, coff+c] * seg[b, c(n)]
__device__ __forceinline__ void seg_accum(const float* __restrict__ p, int cnt,
    const float* __restrict__ WL, int coff, int sC, int sN, float fs,
    long n0, float acc[4])
{
#pragma unroll 4
  for (int c = 0; c < cnt; ++c) {
    float w = WL[coff + c] * fs;
#pragma unroll
    for (int m = 0; m < 4; ++m)
      acc[m] = fmaf(w, p[(size_t)c * sC + (size_t)(n0 + m) * sN], acc[m]);
  }
}

__launch_bounds__(256)
__global__ void proj_kernel(
    const float* __restrict__ W, int wld, const float* __restrict__ bias,
    float* __restrict__ out, int OUT, int N,
    const float* __restrict__ s0, int c0, int o0, int sC0, int sN0, float f0,
    const float* __restrict__ s1, int c1, int o1, int sC1, int sN1, float f1,
    const float* __restrict__ s2, int c2, int o2, int sC2, int sN2, float f2,
    const float* __restrict__ s3, int c3, int o3, int sC3, int sN3, float f3)
{
  int b = blockIdx.y;
  int lane = threadIdx.x % OUT;
  int grp = threadIdx.x / OUT;
  int grps = blockDim.x / OUT;
  long n0 = ((long)blockIdx.x * grps + grp) * 4;
  if (n0 >= N) return;
  float acc[4];
  float bv = bias ? bias[lane] : 0.0f;
#pragma unroll
  for (int m = 0; m < 4; ++m) acc[m] = bv;
  const float* WL = W + (size_t)lane * wld;
  if (c0 > 0) seg_accum(s0 + (size_t)b * c0 * N, c0, WL, o0, sC0, sN0, f0, n0, acc);
  if (c1 > 0) seg_accum(s1 + (size_t)b * c1 * N, c1, WL, o1, sC1, sN1, f1, n0, acc);
  if (c2 > 0) seg_accum(s2 + (size_t)b * c2 * N, c2, WL, o2, sC2, sN2, f2, n0, acc);
  if (c3 > 0) seg_accum(s3 + (size_t)b * c3 * N, c3, WL, o3, sC3, sN3, f3, n0, acc);
#pragma unroll
  for (int m = 0; m < 4; ++m)
    out[((size_t)b * N + n0 + m) * OUT + lane] = acc[m];
}

// ------------------------------------------------------------- groupnorm ----
__launch_bounds__(256)
__global__ void gn1_stats_kernel(const float* __restrict__ G1, const float* __restrict__ Bx,
    const int* __restrict__ idx0, float* __restrict__ stats1, int N)
{
  __shared__ float red[4][4][2];
  int b = blockIdx.y;
  int lane = threadIdx.x & 63, wav = threadIdx.x >> 6;
  float sum = 0.f, sq = 0.f;
  for (int n = blockIdx.x * 4 + wav; n < N; n += gridDim.x * 4) {
    const int* ip = idx0 + ((size_t)b * N + n) * 16;
    float bx = Bx[((size_t)b * N + n) * 64 + lane];
#pragma unroll
    for (int k = 0; k < 16; ++k) {
      int m = ip[k];
      float y = G1[((size_t)b * N + m) * 64 + lane] - bx;
      sum += y; sq += y * y;
    }
  }
#pragma unroll
  for (int off = 1; off < 16; off <<= 1) {
    sum += __shfl_xor(sum, off, 64);
    sq += __shfl_xor(sq, off, 64);
  }
  int g = lane >> 4;
  if ((lane & 15) == 0) { red[wav][g][0] = sum; red[wav][g][1] = sq; }
  __syncthreads();
  if (threadIdx.x < 8) {
    int gg = threadIdx.x >> 1, s = threadIdx.x & 1;
    float v = red[0][gg][s] + red[1][gg][s] + red[2][gg][s] + red[3][gg][s];
    atomicAdd(&stats1[(b * 4 + gg) * 2 + s], v);
  }
}

__global__ void gn_finalize_kernel(const float* __restrict__ raw, float* __restrict__ mi, float cnt)
{
  int i = threadIdx.x;
  if (i < 8) {
    float s = raw[i * 2], q = raw[i * 2 + 1];
    float m = s / cnt;
    float v = q / cnt - m * m;
    mi[i * 2] = m;
    mi[i * 2 + 1] = rsqrtf(v + 1e-5f);
  }
}

// ------------------------------------------------------------- flow conv2 ----
__launch_bounds__(256)
__global__ void conv2_kernel(const float* __restrict__ G1, const float* __restrict__ Bx,
    const int* __restrict__ idx0, const float* __restrict__ fw2, const float* __restrict__ fb2,
    const float* __restrict__ fg1, const float* __restrict__ fbe1,
    const float* __restrict__ mi1, float* __restrict__ y2max, float* __restrict__ y2min,
    float* __restrict__ stats2, int N)
{
  __shared__ __align__(16) float Wl[64][68];
  __shared__ __align__(16) float x2[4][16][64];
  __shared__ float red[4][4][2];
  int b = blockIdx.y;
  int lane = threadIdx.x & 63, wav = threadIdx.x >> 6;
  for (int i = threadIdx.x; i < 64 * 64; i += 256) Wl[i >> 6][i & 63] = fw2[i];
  int g = lane >> 4;
  float mu1 = mi1[(b * 4 + g) * 2], inv1 = mi1[(b * 4 + g) * 2 + 1];
  float sc1 = fg1[lane] * inv1;
  float sh1 = fbe1[lane] - mu1 * sc1;
  float fb2l = fb2[lane];
  float sum = 0.f, sq = 0.f;
  __syncthreads();
  for (int n = blockIdx.x * 4 + wav; n < N; n += gridDim.x * 4) {
    const int* ip = idx0 + ((size_t)b * N + n) * 16;
    float bx = Bx[((size_t)b * N + n) * 64 + lane];
#pragma unroll
    for (int k = 0; k < 16; ++k) {
      int m = ip[k];
      float y = G1[((size_t)b * N + m) * 64 + lane] - bx;
      float tv = y * sc1 + sh1;
      x2[wav][k][lane] = tv >= 0.f ? tv : 0.1f * tv;
    }
    __syncthreads();
    float acc[16];
#pragma unroll
    for (int k = 0; k < 16; ++k) acc[k] = fb2l;
    for (int c4 = 0; c4 < 16; ++c4) {
      float4 w4 = *(const float4*)&Wl[lane][c4 * 4];
#pragma unroll
      for (int k = 0; k < 16; ++k) {
        float4 x4 = *(const float4*)&x2[wav][k][c4 * 4];
        acc[k] = fmaf(w4.x, x4.x, acc[k]);
        acc[k] = fmaf(w4.y, x4.y, acc[k]);
        acc[k] = fmaf(w4.z, x4.z, acc[k]);
        acc[k] = fmaf(w4.w, x4.w, acc[k]);
      }
    }
    float mx = -3.0e38f, mn = 3.0e38f;
#pragma unroll
    for (int k = 0; k < 16; ++k) {
      mx = fmaxf(mx, acc[k]); mn = fminf(mn, acc[k]);
      sum += acc[k]; sq += acc[k] * acc[k];
    }
    y2max[((size_t)b * N + n) * 64 + lane] = mx;
    y2min[((size_t)b * N + n) * 64 + lane] = mn;
    __syncthreads();
  }
#pragma unroll
  for (int off = 1; off < 16; off <<= 1) {
    sum += __shfl_xor(sum, off, 64);
    sq += __shfl_xor(sq, off, 64);
  }
  if ((lane & 15) == 0) { red[wav][g][0] = sum; red[wav][g][1] = sq; }
  __syncthreads();
  if (threadIdx.x < 8) {
    int gg = threadIdx.x >> 1, s = threadIdx.x & 1;
    float v = red[0][gg][s] + red[1][gg][s] + red[2][gg][s] + red[3][gg][s];
    atomicAdd(&stats2[(b * 4 + gg) * 2 + s], v);
  }
}

__launch_bounds__(256)
__global__ void flow_feat_kernel(const float* __restrict__ y2max, const float* __restrict__ y2min,
    const float* __restrict__ mi2, const float* __restrict__ fg2, const float* __restrict__ fbe2,
    float* __restrict__ ff, int N)
{
  size_t i = (size_t)blockIdx.x * blockDim.x + threadIdx.x;
  if (i >= (size_t)B_SZ * N * 64) return;
  int c = i & 63;
  size_t pn = i >> 6;
  int b = (int)(pn / N);
  int g = c >> 4;
  float mu = mi2[(b * 4 + g) * 2], inv = mi2[(b * 4 + g) * 2 + 1];
  float sc = fg2[c] * inv;
  float sh = fbe2[c] - mu * sc;
  float y = (sc >= 0.0f) ? y2max[i] : y2min[i];
  float v = y * sc + sh;
  ff[i] = v >= 0.0f ? v : 0.1f * v;
}

// ------------------------------------------------------------------ gates ----
__launch_bounds__(256)
__global__ void gate_zr_kernel(const float* __restrict__ Sz, const float* __restrict__ Xz,
    const float* __restrict__ Sr, const float* __restrict__ Xr,
    const float* __restrict__ state, const int* __restrict__ idx0,
    float* __restrict__ zo, float* __restrict__ rs, int N)
{
  int b = blockIdx.y;
  int lane = threadIdx.x & 63, wav = threadIdx.x >> 6;
  int n = blockIdx.x * 4 + wav;
  const int* ip = idx0 + ((size_t)b * N + n) * 16;
  float mz = -3.0e38f, mr = -3.0e38f;
#pragma unroll
  for (int k = 0; k < 16; ++k) {
    size_t mo = ((size_t)b * N + ip[k]) * 64 + lane;
    mz = fmaxf(mz, Sz[mo]);
    mr = fmaxf(mr, Sr[mo]);
  }
  size_t no = ((size_t)b * N + n) * 64 + lane;
  float z = 1.f / (1.f + expf(-(mz - Xz[no])));
  float r = 1.f / (1.f + expf(-(mr - Xr[no])));
  zo[no] = z;
  rs[no] = r * state[((size_t)b * 64 + lane) * N + n];
}

__launch_bounds__(256)
__global__ void gate_q_ns_kernel(const float* __restrict__ Sq, const float* __restrict__ Xq,
    const float* __restrict__ zo, const float* __restrict__ state, const int* __restrict__ idx0,
    float* __restrict__ ns, int N)
{
  int b = blockIdx.y;
  int lane = threadIdx.x & 63, wav = threadIdx.x >> 6;
  int n = blockIdx.x * 4 + wav;
  const int* ip = idx0 + ((size_t)b * N + n) * 16;
  float mq = -3.0e38f;
#pragma unroll
  for (int k = 0; k < 16; ++k)
    mq = fmaxf(mq, Sq[((size_t)b * N + ip[k]) * 64 + lane]);
  size_t no = ((size_t)b * N + n) * 64 + lane;
  float q = tanhf(mq - Xq[no]);
  float z = zo[no];
  float st = state[((size_t)b * 64 + lane) * N + n];
  ns[no] = (1.f - z) * st + z * q;
}

// ------------------------------------------------------------------ align ----
__launch_bounds__(256)
__global__ void align_kernel(const float* __restrict__ U, const float* __restrict__ V,
    const float* __restrict__ wa2, const float* __restrict__ ba2,
    const float* __restrict__ ns, const int* __restrict__ idx1,
    float* __restrict__ out, int N)
{
  __shared__ __align__(16) float Wl[64][132];
  __shared__ __align__(16) float xk[4][16][128];
  int b = blockIdx.y;
  int lane = threadIdx.x & 63, wav = threadIdx.x >> 6;
  for (int i = threadIdx.x; i < 64 * 128; i += 256) Wl[i >> 7][i & 127] = wa2[i];
  float ba = ba2[lane];
  __syncthreads();
  int n = blockIdx.x * 4 + wav;
  const int* ip = idx1 + ((size_t)b * N + n) * 16;
  int mk[16];
#pragma unroll
  for (int k = 0; k < 16; ++k) mk[k] = ip[k];
  const float* Vp = V + ((size_t)b * N + n) * 128;
  float v0 = Vp[lane], v1 = Vp[64 + lane];
#pragma unroll
  for (int k = 0; k < 16; ++k) {
    const float* Up = U + ((size_t)b * N + mk[k]) * 128;
    float a = Up[lane] + v0;
    float c2 = Up[64 + lane] + v1;
    xk[wav][k][lane] = a >= 0.f ? a : 0.1f * a;
    xk[wav][k][64 + lane] = c2 >= 0.f ? c2 : 0.1f * c2;
  }
  __syncthreads();
  float acc[16];
#pragma unroll
  for (int k = 0; k < 16; ++k) acc[k] = ba;
  for (int c4 = 0; c4 < 32; ++c4) {
    float4 w4 = *(const float4*)&Wl[lane][c4 * 4];
#pragma unroll
    for (int k = 0; k < 16; ++k) {
      float4 x4 = *(const float4*)&xk[wav][k][c4 * 4];
      acc[k] = fmaf(w4.x, x4.x, acc[k]);
      acc[k] = fmaf(w4.y, x4.y, acc[k]);
      acc[k] = fmaf(w4.z, x4.z, acc[k]);
      acc[k] = fmaf(w4.w, x4.w, acc[k]);
    }
  }
  float m = acc[0];
#pragma unroll
  for (int k = 1; k < 16; ++k) m = fmaxf(m, acc[k]);
  float s = 0.f;
#pragma unroll
  for (int k = 0; k < 16; ++k) { acc[k] = expf(acc[k] - m); s += acc[k]; }
  float rinv = 1.0f / s;
  float o = 0.f;
#pragma unroll
  for (int k = 0; k < 16; ++k)
    o += acc[k] * rinv * ns[((size_t)b * N + mk[k]) * 64 + lane];
  out[((size_t)b * 64 + lane) * N + n] = o;
}

// ------------------------------------------------------------------ launch ----
extern "C" void kernel_launch(void* const* d_in, const int* in_sizes, int n_in,
                              void* d_out, int out_size, void* d_ws, size_t ws_size,
                              hipStream_t stream) {
  (void)n_in; (void)out_size; (void)ws_size;
  const float* xyz0 = (const float*)d_in[0];
  const float* xyz1 = (const float*)d_in[1];
  const float* state = (const float*)d_in[2];
  const float* corr0 = (const float*)d_in[3];
  const float* feat0 = (const float*)d_in[4];
  const float* feat1 = (const float*)d_in[5];
  const float* flow0 = (const float*)d_in[6];
  const float* fw1 = (const float*)d_in[7];
  const float* fb1 = (const float*)d_in[8];
  const float* fg1 = (const float*)d_in[9];
  const float* fbe1 = (const float*)d_in[10];
  const float* fw2 = (const float*)d_in[11];
  const float* fb2 = (const float*)d_in[12];
  const float* fg2 = (const float*)d_in[13];
  const float* fbe2 = (const float*)d_in[14];
  const float* wz = (const float*)d_in[15];
  const float* bz = (const float*)d_in[16];
  const float* wr = (const float*)d_in[17];
  const float* br = (const float*)d_in[18];
  const float* wq = (const float*)d_in[19];
  const float* bq = (const float*)d_in[20];
  const float* wa1 = (const float*)d_in[21];
  const float* ba1 = (const float*)d_in[22];
  const float* wa2 = (const float*)d_in[23];
  const float* ba2 = (const float*)d_in[24];
  float* out = (float*)d_out;

  const int N = in_sizes[0] / (3 * B_SZ);  // 4096
  char* wsb = (char*)d_ws;
  size_t off = 0;
  auto take = [&](size_t bytes) -> char* {
    char* p = wsb + off;
    off += (bytes + 255) & ~(size_t)255;
    return p;
  };
  const size_t PN = (size_t)B_SZ * N;
  float* pd   = (float*)take(PN * 128 * 4);   // U (align proj) ; scratch
  float* pi   = (float*)take(PN * 128 * 4);   // V (align proj) ; scratch
  float4* pk0 = (float4*)take(PN * 4 * 4);    // packed xyz0 targets
  int*   idx0 = (int*)  take(PN * 16 * 4);
  int*   idx1 = (int*)  take(PN * 16 * 4);
  float* G1   = (float*)take(PN * 64 * 4);
  float* Bx   = (float*)take(PN * 64 * 4);
  float* y2mx = (float*)take(PN * 64 * 4);
  float* y2mn = (float*)take(PN * 64 * 4);
  float* ff   = (float*)take(PN * 64 * 4);
  float* Sz   = (float*)take(PN * 64 * 4);
  float* Xz   = (float*)take(PN * 64 * 4);
  float* Sr   = (float*)take(PN * 64 * 4);
  float* Xr   = (float*)take(PN * 64 * 4);
  float* Sq   = (float*)take(PN * 64 * 4);
  float* Xq   = (float*)take(PN * 64 * 4);
  float* zg   = (float*)take(PN * 64 * 4);
  float* rs   = (float*)take(PN * 64 * 4);
  float* ns   = (float*)take(PN * 64 * 4);
  float* stats = (float*)take(256);
  float* raw1 = stats, *raw2 = stats + 16, *mi1 = stats + 32, *mi2 = stats + 48;
  float* U = pd;
  float* V = pi;

  const float* FNUL = nullptr;
  const float cntv = 16.0f * N * 16.0f;

  hipMemsetAsync(raw1, 0, 32 * sizeof(float), stream);

  // KNN: pack xyz0 targets once, then one wave per query, no merge pass.
  pack_kernel<<<dim3((N + 255) / 256, B_SZ), 256, 0, stream>>>(xyz0, pk0, N);
  knn_wave_kernel<<<dim3(N / 4, B_SZ), 256, 0, stream>>>(pk0, xyz0, idx0, N);
  knn_wave_kernel<<<dim3(N / 4, B_SZ), 256, 0, stream>>>(pk0, xyz1, idx1, N);

  dim3 pj64(N / 16, B_SZ), pj128(N / 8, B_SZ);
  // flow conv1 factored: G1 = fw1[:,:3]@flow0 + fw1[:,3:]@xyz0 + fb1 ; Bx = fw1[:,3:]@xyz0
  proj_kernel<<<pj64, 256, 0, stream>>>(fw1, 6, fb1, G1, 64, N,
      flow0, 3, 0, N, 1, 1.f,  xyz0, 3, 3, N, 1, 1.f,
      FNUL, 0, 0, 1, 1, 0.f,   FNUL, 0, 0, 1, 1, 0.f);
  proj_kernel<<<pj64, 256, 0, stream>>>(fw1, 6, FNUL, Bx, 64, N,
      xyz0, 3, 3, N, 1, 1.f,   FNUL, 0, 0, 1, 1, 0.f,
      FNUL, 0, 0, 1, 1, 0.f,   FNUL, 0, 0, 1, 1, 0.f);

  gn1_stats_kernel<<<dim3(128, B_SZ), 256, 0, stream>>>(G1, Bx, idx0, raw1, N);
  gn_finalize_kernel<<<1, 64, 0, stream>>>(raw1, mi1, cntv);
  conv2_kernel<<<dim3(128, B_SZ), 256, 0, stream>>>(G1, Bx, idx0, fw2, fb2, fg1, fbe1,
      mi1, y2mx, y2mn, raw2, N);
  gn_finalize_kernel<<<1, 64, 0, stream>>>(raw2, mi2, cntv);
  flow_feat_kernel<<<dim3((unsigned)(PN * 64 / 256)), 256, 0, stream>>>(y2mx, y2mn, mi2, fg2, fbe2, ff, N);

  // gate projections: S* over targets, X* = Wxyz@xyz0 at query
  proj_kernel<<<pj64, 256, 0, stream>>>(wz, 195, bz, Sz, 64, N,
      corr0, 64, 0, N, 1, 1.f,  ff, 64, 64, 1, 64, 1.f,
      state, 64, 128, N, 1, 1.f, xyz0, 3, 192, N, 1, 1.f);
  proj_kernel<<<pj64, 256, 0, stream>>>(wz, 195, FNUL, Xz, 64, N,
      xyz0, 3, 192, N, 1, 1.f,  FNUL, 0, 0, 1, 1, 0.f,
      FNUL, 0, 0, 1, 1, 0.f,    FNUL, 0, 0, 1, 1, 0.f);
  proj_kernel<<<pj64, 256, 0, stream>>>(wr, 195, br, Sr, 64, N,
      corr0, 64, 0, N, 1, 1.f,  ff, 64, 64, 1, 64, 1.f,
      state, 64, 128, N, 1, 1.f, xyz0, 3, 192, N, 1, 1.f);
  proj_kernel<<<pj64, 256, 0, stream>>>(wr, 195, FNUL, Xr, 64, N,
      xyz0, 3, 192, N, 1, 1.f,  FNUL, 0, 0, 1, 1, 0.f,
      FNUL, 0, 0, 1, 1, 0.f,    FNUL, 0, 0, 1, 1, 0.f);

  gate_zr_kernel<<<dim3(N / 4, B_SZ), 256, 0, stream>>>(Sz, Xz, Sr, Xr, state, idx0, zg, rs, N);

  proj_kernel<<<pj64, 256, 0, stream>>>(wq, 195, bq, Sq, 64, N,
      corr0, 64, 0, N, 1, 1.f,  ff, 64, 64, 1, 64, 1.f,
      rs, 64, 128, 1, 64, 1.f,  xyz0, 3, 192, N, 1, 1.f);
  proj_kernel<<<pj64, 256, 0, stream>>>(wq, 195, FNUL, Xq, 64, N,
      xyz0, 3, 192, N, 1, 1.f,  FNUL, 0, 0, 1, 1, 0.f,
      FNUL, 0, 0, 1, 1, 0.f,    FNUL, 0, 0, 1, 1, 0.f);

  gate_q_ns_kernel<<<dim3(N / 4, B_SZ), 256, 0, stream>>>(Sq, Xq, zg, state, idx0, ns, N);

  // align projections: U over targets (feat0 + xyz0), V per query (feat1 - xyz1 + ba1)
  proj_kernel<<<pj128, 256, 0, stream>>>(wa1, 259, FNUL, U, 128, N,
      feat0, 128, 0, N, 1, 1.f, xyz0, 3, 256, N, 1, 1.f,
      FNUL, 0, 0, 1, 1, 0.f,    FNUL, 0, 0, 1, 1, 0.f);
  proj_kernel<<<pj128, 256, 0, stream>>>(wa1, 259, ba1, V, 128, N,
      feat1, 128, 128, N, 1, 1.f, xyz1, 3, 256, N, 1, -1.f,
      FNUL, 0, 0, 1, 1, 0.f,      FNUL, 0, 0, 1, 1, 0.f);

  align_kernel<<<dim3(N / 4, B_SZ), 256, 0, stream>>>(U, V, wa2, ba2, ns, idx1, out, N);
}